// Round 4
// baseline (158.170 us; speedup 1.0000x reference)
//
#include <hip/hip_runtime.h>

#define BB 8
#define LL 4096
#define DM 64
#define DI 128
#define NS 16
#define CSZ 64    // tokens per chunk/block
#define NCH 64    // LL/CSZ

__device__ __forceinline__ float siluf(float x) {
  return x / (1.f + __expf(-x));
}
__device__ __forceinline__ float softplusf(float x) {
  return x > 20.f ? x : log1pf(__expf(x));
}

// ---------------- K1: in_proj  xr = x @ Win^T ; upre = xr[:, :128]; gate = silu(xr[:, 128:])
// 512 blocks: (b, 32 token-chunks of 128, 2 j-halves). LDS 67.6KB -> 2 blocks/CU.
__global__ __launch_bounds__(256) void k_inproj(
    const float* __restrict__ x, const float* __restrict__ Win,
    float* __restrict__ upre, float* __restrict__ gate) {
  __shared__ float xs[64][132];   // [k][t]
  __shared__ float wT[64][132];   // [k][j]
  const int bid = blockIdx.x;
  const int jh = bid & 1;
  const int lc = (bid >> 1) & 31;
  const int b  = bid >> 6;
  const int l0 = lc * 128;
  const int tid = threadIdx.x;
  for (int i = 0; i < 8; ++i) {
    int idx = (i * 256 + tid) * 4;
    int t = idx >> 6, k = idx & 63;
    float4 v = *(const float4*)(x + ((size_t)b * LL + l0 + t) * DM + k);
    xs[k][t] = v.x; xs[k + 1][t] = v.y; xs[k + 2][t] = v.z; xs[k + 3][t] = v.w;
  }
  for (int i = 0; i < 8; ++i) {
    int idx = (i * 256 + tid) * 4;
    int j = idx >> 6, k = idx & 63;
    float4 v = *(const float4*)(Win + (size_t)(jh * 128 + j) * DM + k);
    wT[k][j] = v.x; wT[k + 1][j] = v.y; wT[k + 2][j] = v.z; wT[k + 3][j] = v.w;
  }
  __syncthreads();
  const int tg = (tid >> 4) * 8;
  const int j0 = (tid & 15) * 8;
  float acc[8][8];
#pragma unroll
  for (int i = 0; i < 8; ++i)
#pragma unroll
    for (int j = 0; j < 8; ++j) acc[i][j] = 0.f;
  for (int k = 0; k < 64; ++k) {
    float av[8], wv[8];
    *(float4*)&av[0] = *(const float4*)&xs[k][tg];
    *(float4*)&av[4] = *(const float4*)&xs[k][tg + 4];
    *(float4*)&wv[0] = *(const float4*)&wT[k][j0];
    *(float4*)&wv[4] = *(const float4*)&wT[k][j0 + 4];
#pragma unroll
    for (int i = 0; i < 8; ++i)
#pragma unroll
      for (int j = 0; j < 8; ++j) acc[i][j] = fmaf(av[i], wv[j], acc[i][j]);
  }
  for (int i = 0; i < 8; ++i) {
    size_t row = ((size_t)b * LL + l0 + tg + i);
    if (jh == 0) {
      *(float4*)(upre + row * DI + j0) =
          make_float4(acc[i][0], acc[i][1], acc[i][2], acc[i][3]);
      *(float4*)(upre + row * DI + j0 + 4) =
          make_float4(acc[i][4], acc[i][5], acc[i][6], acc[i][7]);
    } else {
      *(float4*)(gate + row * DI + j0) =
          make_float4(siluf(acc[i][0]), siluf(acc[i][1]), siluf(acc[i][2]), siluf(acc[i][3]));
      *(float4*)(gate + row * DI + j0 + 4) =
          make_float4(siluf(acc[i][4]), siluf(acc[i][5]), siluf(acc[i][6]), siluf(acc[i][7]));
    }
  }
}

// ---------------- K2 (v4): conv+silu -> us2/u_g; x_proj -> (drs, bs2, Bm, Cm);
// dt_proj+softplus -> delta_g; LOCAL SCAN over 64 tokens -> Aprod, Hend.
// 512 blocks: (b, 64 chunks of 64 tok). LDS 38.4KB -> 4 blocks/CU.
__global__ __launch_bounds__(256) void k_front(
    const float* __restrict__ upre,
    const float* __restrict__ convw, const float* __restrict__ convb,
    const float* __restrict__ xpw, const float* __restrict__ dtw,
    const float* __restrict__ dtb, const float* __restrict__ Alog,
    float* __restrict__ u_g, float* __restrict__ delta_g,
    float* __restrict__ Bm_g, float* __restrict__ Cm_g,
    float* __restrict__ Aprod, float* __restrict__ Hend) {
  __shared__ float us2[CSZ][129];  // [t][d], stride 129 -> conflict-free both axes
  __shared__ float bs2[CSZ][17];   // [t][n]
  __shared__ float drs[CSZ][4];    // [t][r]
  const int b = blockIdx.x >> 6;
  const int c = blockIdx.x & 63;
  const int l0 = c * CSZ;
  const int tid = threadIdx.x;
  const size_t tokbase = (size_t)b * LL + l0;
  // Phase A: depthwise conv(4) + bias + silu. thread <-> (d, 4-token group)
  for (int i = 0; i < 8; ++i) {
    int idx = i * 256 + tid;
    int d = idx & 127;
    int t0 = (idx >> 7) * 4;
    float4 cw = *(const float4*)(convw + d * 4);
    float cb = convb[d];
    float p[7];
#pragma unroll
    for (int s = 0; s < 7; ++s) {
      int li = l0 + t0 - 3 + s;
      p[s] = (li >= 0) ? upre[((size_t)b * LL + li) * DI + d] : 0.f;
    }
#pragma unroll
    for (int j = 0; j < 4; ++j) {
      float a = cb;
      a = fmaf(p[j], cw.x, a);
      a = fmaf(p[j + 1], cw.y, a);
      a = fmaf(p[j + 2], cw.z, a);
      a = fmaf(p[j + 3], cw.w, a);
      float uo = siluf(a);
      us2[t0 + j][d] = uo;
      u_g[(tokbase + t0 + j) * DI + d] = uo;
    }
  }
  __syncthreads();
  // Phase B: x_proj. wave w computes rows [9w, 9w+9) for 64 tokens (lane = token).
  {
    const int wid = __builtin_amdgcn_readfirstlane(tid >> 6);
    const int lane = tid & 63;
    const size_t tok = tokbase + lane;
    float acc[9];
#pragma unroll
    for (int jj = 0; jj < 9; ++jj) acc[jj] = 0.f;
    const float* w0 = xpw + (size_t)(9 * wid) * DI;
    for (int k = 0; k < 128; k += 4) {
      float uv[4];
#pragma unroll
      for (int q = 0; q < 4; ++q) uv[q] = us2[lane][k + q];
#pragma unroll
      for (int jj = 0; jj < 9; ++jj) {
        const float* wr = w0 + jj * DI + k;
        acc[jj] = fmaf(uv[0], wr[0], acc[jj]);
        acc[jj] = fmaf(uv[1], wr[1], acc[jj]);
        acc[jj] = fmaf(uv[2], wr[2], acc[jj]);
        acc[jj] = fmaf(uv[3], wr[3], acc[jj]);
      }
    }
#pragma unroll
    for (int jj = 0; jj < 9; ++jj) {
      int j = 9 * wid + jj;
      if (j < 4) drs[lane][j] = acc[jj];
      else if (j < 20) { bs2[lane][j - 4] = acc[jj]; Bm_g[tok * NS + (j - 4)] = acc[jj]; }
      else Cm_g[tok * NS + (j - 20)] = acc[jj];
    }
  }
  __syncthreads();
  // Phase C: dt_proj + softplus -> delta_g (global, for k_back)
  for (int i = 0; i < 8; ++i) {
    int idx = i * 256 + tid;
    int t = idx >> 5;
    int d = (idx & 31) * 4;
    float4 dr = *(const float4*)&drs[t][0];
    float4 ov;
    float* po = &ov.x;
#pragma unroll
    for (int m = 0; m < 4; ++m) {
      float4 w = *(const float4*)(dtw + (size_t)(d + m) * 4);
      float v = fmaf(dr.x, w.x, fmaf(dr.y, w.y, fmaf(dr.z, w.z, fmaf(dr.w, w.w, dtb[d + m]))));
      po[m] = softplusf(v);
    }
    *(float4*)(delta_g + (tokbase + t) * DI + d) = ov;
  }
  // Phase D: local scan over 64 tokens (delta recomputed in-register) -> Aprod, Hend
  {
    const int d = tid >> 1;
    const int n0 = (tid & 1) * 8;
    float4 wdt = *(const float4*)(dtw + (size_t)d * 4);
    float bdt = dtb[d];
    float a[8], h[8], ap[8];
#pragma unroll
    for (int m = 0; m < 8; ++m) {
      a[m] = -__expf(Alog[d * NS + n0 + m]);
      h[m] = 0.f; ap[m] = 1.f;
    }
    for (int l = 0; l < CSZ; ++l) {
      float d0 = drs[l][0], d1 = drs[l][1], d2 = drs[l][2], d3 = drs[l][3];
      float dl = softplusf(
          fmaf(d0, wdt.x, fmaf(d1, wdt.y, fmaf(d2, wdt.z, fmaf(d3, wdt.w, bdt)))));
      float uu = us2[l][d];
      float du = dl * uu;
#pragma unroll
      for (int m = 0; m < 8; ++m) {
        float dA = __expf(dl * a[m]);
        ap[m] *= dA;
        h[m] = fmaf(dA, h[m], du * bs2[l][n0 + m]);
      }
    }
    size_t base = ((size_t)(b * NCH + c)) * 2048 + (size_t)tid * 8;
    *(float4*)(Aprod + base)     = make_float4(ap[0], ap[1], ap[2], ap[3]);
    *(float4*)(Aprod + base + 4) = make_float4(ap[4], ap[5], ap[6], ap[7]);
    *(float4*)(Hend + base)      = make_float4(h[0], h[1], h[2], h[3]);
    *(float4*)(Hend + base + 4)  = make_float4(h[4], h[5], h[6], h[7]);
  }
}

// ---------------- K3: 2-level prefix over 64 chunks per channel. 512 blocks x (8 seg x 32 ch).
// Hin aliases Aprod (elements copied to registers before overwrite).
__global__ __launch_bounds__(256) void k_prefix2(
    const float* __restrict__ Aprod, const float* __restrict__ Hend,
    float* __restrict__ Hin) {
  __shared__ float sA[8][33], sB[8][33], sH[8][33];
  const int chl = threadIdx.x & 31;
  const int seg = threadIdx.x >> 5;
  const int ch = blockIdx.x * 32 + chl;
  const int b = ch >> 11, dn = ch & 2047;
  float av[8], bv[8];
  float A = 1.f, Bc = 0.f;
#pragma unroll
  for (int i = 0; i < 8; ++i) {
    int c = seg * 8 + i;
    size_t idx = ((size_t)(b * NCH + c)) * 2048 + dn;
    av[i] = Aprod[idx];
    bv[i] = Hend[idx];
    Bc = fmaf(av[i], Bc, bv[i]);
    A *= av[i];
  }
  sA[seg][chl] = A; sB[seg][chl] = Bc;
  __syncthreads();
  if (threadIdx.x < 32) {
    float h = 0.f;
#pragma unroll
    for (int s = 0; s < 8; ++s) {
      sH[s][threadIdx.x] = h;
      h = fmaf(sA[s][threadIdx.x], h, sB[s][threadIdx.x]);
    }
  }
  __syncthreads();
  float h = sH[seg][chl];
#pragma unroll
  for (int i = 0; i < 8; ++i) {
    int c = seg * 8 + i;
    size_t idx = ((size_t)(b * NCH + c)) * 2048 + dn;
    Hin[idx] = h;
    h = fmaf(av[i], h, bv[i]);
  }
}

// ---------------- K4: final scan (Hin) + y=(sum h*C + u*D)*gate -> LDS; out = y @ Wout^T.
// 512 blocks: (b, 64 chunks of 64 tok). LDS 67.8KB -> 2 blocks/CU.
__global__ __launch_bounds__(256) void k_back(
    const float* __restrict__ u_g, const float* __restrict__ delta_g,
    const float* __restrict__ Bm_g, const float* __restrict__ Cm_g,
    const float* __restrict__ gate, const float* __restrict__ Hin,
    const float* __restrict__ Alog, const float* __restrict__ Dw,
    const float* __restrict__ Wout, float* __restrict__ out) {
  __shared__ float y2[CSZ][129];   // [t][d]
  __shared__ float wotT[DI][68];   // [d][o]
  const int b = blockIdx.x >> 6;
  const int c = blockIdx.x & 63;
  const int l0 = c * CSZ;
  const int tid = threadIdx.x;
  const size_t tokbase = (size_t)b * LL + l0;
  // stage Wout transposed (64 o x 128 d -> wotT[d][o])
  for (int i = 0; i < 8; ++i) {
    int idx = (i * 256 + tid) * 4;
    int o = idx >> 7, dd = idx & 127;
    float4 v = *(const float4*)(Wout + idx);
    wotT[dd][o] = v.x; wotT[dd + 1][o] = v.y; wotT[dd + 2][o] = v.z; wotT[dd + 3][o] = v.w;
  }
  // scan phase
  {
    const int d = tid >> 1;
    const int n0 = (tid & 1) * 8;
    float a[8], h[8];
    size_t hbase = ((size_t)(b * NCH + c)) * 2048 + (size_t)tid * 8;
    float4 h0 = *(const float4*)(Hin + hbase);
    float4 h1 = *(const float4*)(Hin + hbase + 4);
    h[0] = h0.x; h[1] = h0.y; h[2] = h0.z; h[3] = h0.w;
    h[4] = h1.x; h[5] = h1.y; h[6] = h1.z; h[7] = h1.w;
#pragma unroll
    for (int m = 0; m < 8; ++m) a[m] = -__expf(Alog[d * NS + n0 + m]);
    float Dd = Dw[d];
    for (int l = 0; l < CSZ; ++l) {
      size_t tok = tokbase + l;
      float dl = delta_g[tok * DI + d];
      float uu = u_g[tok * DI + d];
      float du = dl * uu;
      float4 b0 = *(const float4*)(Bm_g + tok * NS + n0);
      float4 b1 = *(const float4*)(Bm_g + tok * NS + n0 + 4);
      float4 c0 = *(const float4*)(Cm_g + tok * NS + n0);
      float4 c1 = *(const float4*)(Cm_g + tok * NS + n0 + 4);
      float bm[8] = {b0.x, b0.y, b0.z, b0.w, b1.x, b1.y, b1.z, b1.w};
      float cm[8] = {c0.x, c0.y, c0.z, c0.w, c1.x, c1.y, c1.z, c1.w};
      float py = 0.f;
#pragma unroll
      for (int m = 0; m < 8; ++m) {
        float dA = __expf(dl * a[m]);
        h[m] = fmaf(dA, h[m], du * bm[m]);
        py = fmaf(h[m], cm[m], py);
      }
      py += __shfl_xor(py, 1);
      if (!(tid & 1)) {
        y2[l][d] = (py + uu * Dd) * gate[tok * DI + d];
      }
    }
  }
  __syncthreads();
  // out-proj: 4 tok x 4 out per thread from LDS
  {
    const int t0 = (tid >> 4) * 4;
    const int o0 = (tid & 15) * 4;
    float acc[4][4];
#pragma unroll
    for (int i = 0; i < 4; ++i)
#pragma unroll
      for (int j = 0; j < 4; ++j) acc[i][j] = 0.f;
    for (int k = 0; k < DI; ++k) {
      float yv[4];
#pragma unroll
      for (int i = 0; i < 4; ++i) yv[i] = y2[t0 + i][k];
      float wv[4];
      *(float4*)&wv[0] = *(const float4*)&wotT[k][o0];
#pragma unroll
      for (int i = 0; i < 4; ++i)
#pragma unroll
        for (int j = 0; j < 4; ++j) acc[i][j] = fmaf(yv[i], wv[j], acc[i][j]);
    }
    for (int i = 0; i < 4; ++i) {
      size_t row = tokbase + t0 + i;
      *(float4*)(out + row * DM + o0) =
          make_float4(acc[i][0], acc[i][1], acc[i][2], acc[i][3]);
    }
  }
}

extern "C" void kernel_launch(void* const* d_in, const int* in_sizes, int n_in,
                              void* d_out, int out_size, void* d_ws, size_t ws_size,
                              hipStream_t stream) {
  const float* x     = (const float*)d_in[0];
  // d_in[1] = latent (unused by reference)
  const float* Win   = (const float*)d_in[2];
  const float* convw = (const float*)d_in[3];
  const float* convb = (const float*)d_in[4];
  const float* xpw   = (const float*)d_in[5];
  const float* dtw   = (const float*)d_in[6];
  const float* dtb   = (const float*)d_in[7];
  const float* Wout  = (const float*)d_in[8];
  const float* Alog  = (const float*)d_in[9];
  const float* Dw    = (const float*)d_in[10];
  float* ws = (float*)d_ws;
  const size_t NT = (size_t)BB * LL;  // 32768 tokens
  float* upre    = ws;
  float* gate    = upre + NT * DI;
  float* u_g     = gate + NT * DI;
  float* delta_g = u_g + NT * DI;
  float* Bm_g    = delta_g + NT * DI;
  float* Cm_g    = Bm_g + NT * NS;
  float* Aprod   = Cm_g + NT * NS;             // reused as Hin
  float* Hend    = Aprod + (size_t)BB * NCH * DI * NS;
  float* Hin     = Aprod;                      // alias: safe (regs hold copies)
  float* outf = (float*)d_out;

  k_inproj<<<512, 256, 0, stream>>>(x, Win, upre, gate);
  k_front<<<512, 256, 0, stream>>>(upre, convw, convb, xpw, dtw, dtb, Alog,
                                   u_g, delta_g, Bm_g, Cm_g, Aprod, Hend);
  k_prefix2<<<512, 256, 0, stream>>>(Aprod, Hend, Hin);
  k_back<<<512, 256, 0, stream>>>(u_g, delta_g, Bm_g, Cm_g, gate, Hin,
                                  Alog, Dw, Wout, outf);
}

// Round 5
// 124.212 us; speedup vs baseline: 1.2734x; 1.2734x over previous
//
#include <hip/hip_runtime.h>

#define BB 8
#define LL 4096
#define DM 64
#define DI 128
#define NS 16
#define CSZ 64    // tokens per chunk/block
#define NCH 64    // LL/CSZ

__device__ __forceinline__ float fast_rcp(float x) {
  float r;
  asm volatile("v_rcp_f32 %0, %1" : "=v"(r) : "v"(x));
  return r;
}
__device__ __forceinline__ float siluf(float x) {
  return x * fast_rcp(1.f + __expf(-x));
}
// softplus(v) = max(v,0) + log1p(exp(-|v|)); cheap __logf version (~1e-7 rel err)
__device__ __forceinline__ float softplusf(float v) {
  return fmaxf(v, 0.f) + __logf(1.f + __expf(-fabsf(v)));
}

// ---------------- K1: in_proj  xr = x @ Win^T ; upre = xr[:, :128]; gate = silu(xr[:, 128:])
// 512 blocks: (b, 32 token-chunks of 128, 2 j-halves).
__global__ __launch_bounds__(256) void k_inproj(
    const float* __restrict__ x, const float* __restrict__ Win,
    float* __restrict__ upre, float* __restrict__ gate) {
  __shared__ float xs[64][132];   // [k][t]
  __shared__ float wT[64][132];   // [k][j]
  const int bid = blockIdx.x;
  const int jh = bid & 1;
  const int lc = (bid >> 1) & 31;
  const int b  = bid >> 6;
  const int l0 = lc * 128;
  const int tid = threadIdx.x;
  for (int i = 0; i < 8; ++i) {
    int idx = (i * 256 + tid) * 4;
    int t = idx >> 6, k = idx & 63;
    float4 v = *(const float4*)(x + ((size_t)b * LL + l0 + t) * DM + k);
    xs[k][t] = v.x; xs[k + 1][t] = v.y; xs[k + 2][t] = v.z; xs[k + 3][t] = v.w;
  }
  for (int i = 0; i < 8; ++i) {
    int idx = (i * 256 + tid) * 4;
    int j = idx >> 6, k = idx & 63;
    float4 v = *(const float4*)(Win + (size_t)(jh * 128 + j) * DM + k);
    wT[k][j] = v.x; wT[k + 1][j] = v.y; wT[k + 2][j] = v.z; wT[k + 3][j] = v.w;
  }
  __syncthreads();
  const int tg = (tid >> 4) * 8;
  const int j0 = (tid & 15) * 8;
  float acc[8][8];
#pragma unroll
  for (int i = 0; i < 8; ++i)
#pragma unroll
    for (int j = 0; j < 8; ++j) acc[i][j] = 0.f;
  for (int k = 0; k < 64; ++k) {
    float av[8], wv[8];
    *(float4*)&av[0] = *(const float4*)&xs[k][tg];
    *(float4*)&av[4] = *(const float4*)&xs[k][tg + 4];
    *(float4*)&wv[0] = *(const float4*)&wT[k][j0];
    *(float4*)&wv[4] = *(const float4*)&wT[k][j0 + 4];
#pragma unroll
    for (int i = 0; i < 8; ++i)
#pragma unroll
      for (int j = 0; j < 8; ++j) acc[i][j] = fmaf(av[i], wv[j], acc[i][j]);
  }
  for (int i = 0; i < 8; ++i) {
    size_t row = ((size_t)b * LL + l0 + tg + i);
    if (jh == 0) {
      *(float4*)(upre + row * DI + j0) =
          make_float4(acc[i][0], acc[i][1], acc[i][2], acc[i][3]);
      *(float4*)(upre + row * DI + j0 + 4) =
          make_float4(acc[i][4], acc[i][5], acc[i][6], acc[i][7]);
    } else {
      *(float4*)(gate + row * DI + j0) =
          make_float4(siluf(acc[i][0]), siluf(acc[i][1]), siluf(acc[i][2]), siluf(acc[i][3]));
      *(float4*)(gate + row * DI + j0 + 4) =
          make_float4(siluf(acc[i][4]), siluf(acc[i][5]), siluf(acc[i][6]), siluf(acc[i][7]));
    }
  }
}

// ---------------- K2 (v5): conv+silu -> us2/u_g; x_proj -> (drs, bs2, Bm, Cm);
// dt_proj+softplus -> dsv(LDS) + delta_g; local scan (delta from LDS) -> Aprod, Hend.
// 512 blocks: (b, 64 chunks of 64 tok). LDS ~74KB -> 2 blocks/CU (grid-capped anyway).
__global__ __launch_bounds__(256) void k_front(
    const float* __restrict__ upre,
    const float* __restrict__ convw, const float* __restrict__ convb,
    const float* __restrict__ xpw, const float* __restrict__ dtw,
    const float* __restrict__ dtb, const float* __restrict__ Alog,
    float* __restrict__ u_g, float* __restrict__ delta_g,
    float* __restrict__ Bm_g, float* __restrict__ Cm_g,
    float* __restrict__ Aprod, float* __restrict__ Hend) {
  __shared__ float us2[CSZ][132];  // [t][d], 16B-aligned rows, conflict-free
  __shared__ float dsv[CSZ][132];  // [t][d] delta
  __shared__ float bs2[CSZ][20];   // [t][n], 16B-aligned rows
  __shared__ float drs[CSZ][4];    // [t][r]
  const int b = blockIdx.x >> 6;
  const int c = blockIdx.x & 63;
  const int l0 = c * CSZ;
  const int tid = threadIdx.x;
  const size_t tokbase = (size_t)b * LL + l0;
  // Phase A: depthwise conv(4) + bias + silu. thread <-> (d, 4-token group)
  for (int i = 0; i < 8; ++i) {
    int idx = i * 256 + tid;
    int d = idx & 127;
    int t0 = (idx >> 7) * 4;
    float4 cw = *(const float4*)(convw + d * 4);
    float cb = convb[d];
    float p[7];
#pragma unroll
    for (int s = 0; s < 7; ++s) {
      int li = l0 + t0 - 3 + s;
      p[s] = (li >= 0) ? upre[((size_t)b * LL + li) * DI + d] : 0.f;
    }
#pragma unroll
    for (int j = 0; j < 4; ++j) {
      float a = cb;
      a = fmaf(p[j], cw.x, a);
      a = fmaf(p[j + 1], cw.y, a);
      a = fmaf(p[j + 2], cw.z, a);
      a = fmaf(p[j + 3], cw.w, a);
      float uo = siluf(a);
      us2[t0 + j][d] = uo;
      u_g[(tokbase + t0 + j) * DI + d] = uo;
    }
  }
  __syncthreads();
  // Phase B: x_proj. wave w computes rows [9w, 9w+9) for 64 tokens (lane = token).
  {
    const int wid = __builtin_amdgcn_readfirstlane(tid >> 6);
    const int lane = tid & 63;
    const size_t tok = tokbase + lane;
    float acc[9];
#pragma unroll
    for (int jj = 0; jj < 9; ++jj) acc[jj] = 0.f;
    const float* w0 = xpw + (size_t)(9 * wid) * DI;
    for (int k = 0; k < 128; k += 4) {
      float uv[4];
      *(float4*)&uv[0] = *(const float4*)&us2[lane][k];
#pragma unroll
      for (int jj = 0; jj < 9; ++jj) {
        const float* wr = w0 + jj * DI + k;
        acc[jj] = fmaf(uv[0], wr[0], acc[jj]);
        acc[jj] = fmaf(uv[1], wr[1], acc[jj]);
        acc[jj] = fmaf(uv[2], wr[2], acc[jj]);
        acc[jj] = fmaf(uv[3], wr[3], acc[jj]);
      }
    }
#pragma unroll
    for (int jj = 0; jj < 9; ++jj) {
      int j = 9 * wid + jj;
      if (j < 4) drs[lane][j] = acc[jj];
      else if (j < 20) { bs2[lane][j - 4] = acc[jj]; Bm_g[tok * NS + (j - 4)] = acc[jj]; }
      else Cm_g[tok * NS + (j - 20)] = acc[jj];
    }
  }
  __syncthreads();
  // Phase C: dt_proj + softplus -> dsv (LDS) + delta_g (global, for k_back)
  for (int i = 0; i < 8; ++i) {
    int idx = i * 256 + tid;
    int t = idx >> 5;
    int d = (idx & 31) * 4;
    float4 dr = *(const float4*)&drs[t][0];
    float4 ov;
    float* po = &ov.x;
#pragma unroll
    for (int m = 0; m < 4; ++m) {
      float4 w = *(const float4*)(dtw + (size_t)(d + m) * 4);
      float v = fmaf(dr.x, w.x, fmaf(dr.y, w.y, fmaf(dr.z, w.z, fmaf(dr.w, w.w, dtb[d + m]))));
      po[m] = softplusf(v);
    }
    *(float4*)&dsv[t][d] = ov;
    *(float4*)(delta_g + (tokbase + t) * DI + d) = ov;
  }
  __syncthreads();
  // Phase D: local scan over 64 tokens (delta from LDS) -> Aprod, Hend
  {
    const int d = tid >> 1;
    const int n0 = (tid & 1) * 8;
    float a[8], h[8], ap[8];
#pragma unroll
    for (int m = 0; m < 8; ++m) {
      a[m] = -__expf(Alog[d * NS + n0 + m]);
      h[m] = 0.f; ap[m] = 1.f;
    }
    for (int l = 0; l < CSZ; ++l) {
      float dl = dsv[l][d];
      float uu = us2[l][d];
      float du = dl * uu;
      float bm[8];
      *(float4*)&bm[0] = *(const float4*)&bs2[l][n0];
      *(float4*)&bm[4] = *(const float4*)&bs2[l][n0 + 4];
#pragma unroll
      for (int m = 0; m < 8; ++m) {
        float dA = __expf(dl * a[m]);
        ap[m] *= dA;
        h[m] = fmaf(dA, h[m], du * bm[m]);
      }
    }
    size_t base = ((size_t)(b * NCH + c)) * 2048 + (size_t)tid * 8;
    *(float4*)(Aprod + base)     = make_float4(ap[0], ap[1], ap[2], ap[3]);
    *(float4*)(Aprod + base + 4) = make_float4(ap[4], ap[5], ap[6], ap[7]);
    *(float4*)(Hend + base)      = make_float4(h[0], h[1], h[2], h[3]);
    *(float4*)(Hend + base + 4)  = make_float4(h[4], h[5], h[6], h[7]);
  }
}

// ---------------- K3: 2-level prefix over 64 chunks per channel. 512 blocks x (8 seg x 32 ch).
__global__ __launch_bounds__(256) void k_prefix2(
    const float* __restrict__ Aprod, const float* __restrict__ Hend,
    float* __restrict__ Hin) {
  __shared__ float sA[8][33], sB[8][33], sH[8][33];
  const int chl = threadIdx.x & 31;
  const int seg = threadIdx.x >> 5;
  const int ch = blockIdx.x * 32 + chl;
  const int b = ch >> 11, dn = ch & 2047;
  float av[8], bv[8];
  float A = 1.f, Bc = 0.f;
#pragma unroll
  for (int i = 0; i < 8; ++i) {
    int c = seg * 8 + i;
    size_t idx = ((size_t)(b * NCH + c)) * 2048 + dn;
    av[i] = Aprod[idx];
    bv[i] = Hend[idx];
    Bc = fmaf(av[i], Bc, bv[i]);
    A *= av[i];
  }
  sA[seg][chl] = A; sB[seg][chl] = Bc;
  __syncthreads();
  if (threadIdx.x < 32) {
    float h = 0.f;
#pragma unroll
    for (int s = 0; s < 8; ++s) {
      sH[s][threadIdx.x] = h;
      h = fmaf(sA[s][threadIdx.x], h, sB[s][threadIdx.x]);
    }
  }
  __syncthreads();
  float h = sH[seg][chl];
#pragma unroll
  for (int i = 0; i < 8; ++i) {
    int c = seg * 8 + i;
    size_t idx = ((size_t)(b * NCH + c)) * 2048 + dn;
    Hin[idx] = h;
    h = fmaf(av[i], h, bv[i]);
  }
}

// ---------------- K4: final scan (Hin) + y=(sum h*C + u*D)*gate -> LDS; out = y @ Wout^T.
// 512 blocks: (b, 64 chunks of 64 tok).
__global__ __launch_bounds__(256) void k_back(
    const float* __restrict__ u_g, const float* __restrict__ delta_g,
    const float* __restrict__ Bm_g, const float* __restrict__ Cm_g,
    const float* __restrict__ gate, const float* __restrict__ Hin,
    const float* __restrict__ Alog, const float* __restrict__ Dw,
    const float* __restrict__ Wout, float* __restrict__ out) {
  __shared__ float y2[CSZ][132];   // [t][d]
  __shared__ float wotT[DI][68];   // [d][o]
  const int b = blockIdx.x >> 6;
  const int c = blockIdx.x & 63;
  const int l0 = c * CSZ;
  const int tid = threadIdx.x;
  const size_t tokbase = (size_t)b * LL + l0;
  // stage Wout transposed (64 o x 128 d -> wotT[d][o])
  for (int i = 0; i < 8; ++i) {
    int idx = (i * 256 + tid) * 4;
    int o = idx >> 7, dd = idx & 127;
    float4 v = *(const float4*)(Wout + idx);
    wotT[dd][o] = v.x; wotT[dd + 1][o] = v.y; wotT[dd + 2][o] = v.z; wotT[dd + 3][o] = v.w;
  }
  // scan phase
  {
    const int d = tid >> 1;
    const int n0 = (tid & 1) * 8;
    float a[8], h[8];
    size_t hbase = ((size_t)(b * NCH + c)) * 2048 + (size_t)tid * 8;
    float4 h0 = *(const float4*)(Hin + hbase);
    float4 h1 = *(const float4*)(Hin + hbase + 4);
    h[0] = h0.x; h[1] = h0.y; h[2] = h0.z; h[3] = h0.w;
    h[4] = h1.x; h[5] = h1.y; h[6] = h1.z; h[7] = h1.w;
#pragma unroll
    for (int m = 0; m < 8; ++m) a[m] = -__expf(Alog[d * NS + n0 + m]);
    float Dd = Dw[d];
    for (int l = 0; l < CSZ; ++l) {
      size_t tok = tokbase + l;
      float dl = delta_g[tok * DI + d];
      float uu = u_g[tok * DI + d];
      float du = dl * uu;
      float bm[8], cm[8];
      *(float4*)&bm[0] = *(const float4*)(Bm_g + tok * NS + n0);
      *(float4*)&bm[4] = *(const float4*)(Bm_g + tok * NS + n0 + 4);
      *(float4*)&cm[0] = *(const float4*)(Cm_g + tok * NS + n0);
      *(float4*)&cm[4] = *(const float4*)(Cm_g + tok * NS + n0 + 4);
      float py = 0.f;
#pragma unroll
      for (int m = 0; m < 8; ++m) {
        float dA = __expf(dl * a[m]);
        h[m] = fmaf(dA, h[m], du * bm[m]);
        py = fmaf(h[m], cm[m], py);
      }
      py += __shfl_xor(py, 1);
      if (!(tid & 1)) {
        y2[l][d] = (py + uu * Dd) * gate[tok * DI + d];
      }
    }
  }
  __syncthreads();
  // out-proj: 4 tok x 4 out per thread from LDS
  {
    const int t0 = (tid >> 4) * 4;
    const int o0 = (tid & 15) * 4;
    float acc[4][4];
#pragma unroll
    for (int i = 0; i < 4; ++i)
#pragma unroll
      for (int j = 0; j < 4; ++j) acc[i][j] = 0.f;
    for (int k = 0; k < DI; ++k) {
      float yv[4];
#pragma unroll
      for (int i = 0; i < 4; ++i) yv[i] = y2[t0 + i][k];
      float wv[4];
      *(float4*)&wv[0] = *(const float4*)&wotT[k][o0];
#pragma unroll
      for (int i = 0; i < 4; ++i)
#pragma unroll
        for (int j = 0; j < 4; ++j) acc[i][j] = fmaf(yv[i], wv[j], acc[i][j]);
    }
    for (int i = 0; i < 4; ++i) {
      size_t row = tokbase + t0 + i;
      *(float4*)(out + row * DM + o0) =
          make_float4(acc[i][0], acc[i][1], acc[i][2], acc[i][3]);
    }
  }
}

extern "C" void kernel_launch(void* const* d_in, const int* in_sizes, int n_in,
                              void* d_out, int out_size, void* d_ws, size_t ws_size,
                              hipStream_t stream) {
  const float* x     = (const float*)d_in[0];
  // d_in[1] = latent (unused by reference)
  const float* Win   = (const float*)d_in[2];
  const float* convw = (const float*)d_in[3];
  const float* convb = (const float*)d_in[4];
  const float* xpw   = (const float*)d_in[5];
  const float* dtw   = (const float*)d_in[6];
  const float* dtb   = (const float*)d_in[7];
  const float* Wout  = (const float*)d_in[8];
  const float* Alog  = (const float*)d_in[9];
  const float* Dw    = (const float*)d_in[10];
  float* ws = (float*)d_ws;
  const size_t NT = (size_t)BB * LL;  // 32768 tokens
  float* upre    = ws;
  float* gate    = upre + NT * DI;
  float* u_g     = gate + NT * DI;
  float* delta_g = u_g + NT * DI;
  float* Bm_g    = delta_g + NT * DI;
  float* Cm_g    = Bm_g + NT * NS;
  float* Aprod   = Cm_g + NT * NS;             // reused as Hin
  float* Hend    = Aprod + (size_t)BB * NCH * DI * NS;
  float* Hin     = Aprod;                      // alias: safe (regs hold copies)
  float* outf = (float*)d_out;

  k_inproj<<<512, 256, 0, stream>>>(x, Win, upre, gate);
  k_front<<<512, 256, 0, stream>>>(upre, convw, convb, xpw, dtw, dtb, Alog,
                                   u_g, delta_g, Bm_g, Cm_g, Aprod, Hend);
  k_prefix2<<<512, 256, 0, stream>>>(Aprod, Hend, Hin);
  k_back<<<512, 256, 0, stream>>>(u_g, delta_g, Bm_g, Cm_g, gate, Hin,
                                  Alog, Dw, Wout, outf);
}